// Round 7
// baseline (390.904 us; speedup 1.0000x reference)
//
#include <hip/hip_runtime.h>
#include <hip/hip_bf16.h>

typedef __attribute__((ext_vector_type(8))) __bf16 bf16x8;
typedef __attribute__((ext_vector_type(4))) float f32x4;

#define DEVI static __device__ __forceinline__

// ---- helpers ---------------------------------------------------------------

DEVI ushort f2bf(float f) {
  unsigned u = __builtin_bit_cast(unsigned, f);
  return (ushort)((u + 0x7fffu + ((u >> 16) & 1u)) >> 16);
}

union BF8 { unsigned u[4]; bf16x8 v; };

// 8 consecutive f32 -> 8 bf16 (RNE) via packed converts
DEVI bf16x8 cvt8(const float* __restrict__ p) {
  const f32x4 a = *(const f32x4*)p;
  const f32x4 b = *(const f32x4*)(p + 4);
  BF8 r;
  asm("v_cvt_pk_bf16_f32 %0, %1, %2" : "=v"(r.u[0]) : "v"(a.x), "v"(a.y));
  asm("v_cvt_pk_bf16_f32 %0, %1, %2" : "=v"(r.u[1]) : "v"(a.z), "v"(a.w));
  asm("v_cvt_pk_bf16_f32 %0, %1, %2" : "=v"(r.u[2]) : "v"(b.x), "v"(b.y));
  asm("v_cvt_pk_bf16_f32 %0, %1, %2" : "=v"(r.u[3]) : "v"(b.z), "v"(b.w));
  return r.v;
}

// 2x f32x4 (8 f32) -> 8 bf16
DEVI bf16x8 cvt8r(f32x4 a, f32x4 b) {
  BF8 r;
  asm("v_cvt_pk_bf16_f32 %0, %1, %2" : "=v"(r.u[0]) : "v"(a.x), "v"(a.y));
  asm("v_cvt_pk_bf16_f32 %0, %1, %2" : "=v"(r.u[1]) : "v"(a.z), "v"(a.w));
  asm("v_cvt_pk_bf16_f32 %0, %1, %2" : "=v"(r.u[2]) : "v"(b.x), "v"(b.y));
  asm("v_cvt_pk_bf16_f32 %0, %1, %2" : "=v"(r.u[3]) : "v"(b.z), "v"(b.w));
  return r.v;
}

// async global->LDS, 16 bytes per lane
DEVI void gload16(const void* g, void* l) {
  __builtin_amdgcn_global_load_lds(
      (const __attribute__((address_space(1))) unsigned*)g,
      (__attribute__((address_space(3))) unsigned*)l, 16, 0, 0);
}

// XCD-aware bijective swizzle (requires nwg % 8 == 0)
DEVI int xcd_swizzle(int bid, int nwg) {
  return (bid & 7) * (nwg >> 3) + (bid >> 3);
}

// ---- weight convert f32 -> bf16 (4 MB each, ~1 us) -------------------------

__global__ __launch_bounds__(256) void cvtw_kernel(
    const float* __restrict__ in, ushort* __restrict__ out, int n8) {
  const int i = blockIdx.x * blockDim.x + threadIdx.x;
  if (i < n8) *(bf16x8*)(out + (size_t)i * 8) = cvt8(in + (size_t)i * 8);
}

// ---- GEMM (f32 A reg-staged, bf16 W): C = A @ W^T + bias, out bf16 ---------
// 128x128 tile, BK=32, 256 threads, 2-phase double buffer. A: global f32 ->
// VGPR -> cvt_pk -> ds_write bf16 (issue-early / write-late, T14). B:
// global_load_lds. Compute phase identical to the pure-bf16 kernel.

__global__ __launch_bounds__(256) void gemm_f32a_2ph(
    const float* __restrict__ A, const ushort* __restrict__ B,
    const float* __restrict__ bias, ushort* __restrict__ C, int N, int K) {
  __shared__ __align__(16) ushort As[2][128 * 32];
  __shared__ __align__(16) ushort Bs[2][128 * 32];
  const int tid = threadIdx.x, lane = tid & 63;
  const int wv = tid >> 6, wr = wv >> 1, wc = wv & 1;
  const int cc = lane & 15, cr = lane >> 4;
  const int ntiles = N >> 7;
  const int work = xcd_swizzle(blockIdx.x, gridDim.x);
  const size_t m0 = (size_t)(work / ntiles) * 128;
  const size_t n0 = (size_t)(work % ntiles) * 128;

  // chunk map: 512 chunks of 8 bf16 per tile, 2 per thread; both-sides swizzle
  const int ch0 = tid, ch1 = tid + 256;
  const int ar0 = ch0 >> 2, au0 = ch0 & 3;
  const int ar1 = ch1 >> 2, au1 = ch1 & 3;
  const int ko0 = (au0 ^ ((ar0 >> 1) & 3)) * 8;
  const int ko1 = (au1 ^ ((ar1 >> 1) & 3)) * 8;
  const float* ag0 = A + (m0 + ar0) * (size_t)K + ko0;   // 8 f32 each
  const float* ag1 = A + (m0 + ar1) * (size_t)K + ko1;
  const ushort* bg0 = B + (n0 + ar0) * (size_t)K + ko0;  // 8 bf16 each
  const ushort* bg1 = B + (n0 + ar1) * (size_t)K + ko1;

  f32x4 acc[4][4] = {};
  const int nt = K >> 5;

  f32x4 ra0, ra1, rb0, rb1;  // A(t+1) staging regs (2 chunks x 8 f32)

  // prologue: stage tile 0
  ra0 = *(const f32x4*)(ag0);
  ra1 = *(const f32x4*)(ag0 + 4);
  rb0 = *(const f32x4*)(ag1);
  rb1 = *(const f32x4*)(ag1 + 4);
  gload16(bg0, &Bs[0][ch0 * 8]);
  gload16(bg1, &Bs[0][ch1 * 8]);
  *(bf16x8*)&As[0][ch0 * 8] = cvt8r(ra0, ra1);
  *(bf16x8*)&As[0][ch1 * 8] = cvt8r(rb0, rb1);
  asm volatile("s_waitcnt lgkmcnt(0)" ::: "memory");

  for (int t = 0; t < nt; ++t) {
    const int cur = t & 1;
    const bool more = (t + 1 < nt);
    if (more) {
      const int kt = (t + 1) << 5;
      ra0 = *(const f32x4*)(ag0 + kt);
      ra1 = *(const f32x4*)(ag0 + kt + 4);
      rb0 = *(const f32x4*)(ag1 + kt);
      rb1 = *(const f32x4*)(ag1 + kt + 4);
      gload16(bg0 + kt, &Bs[cur ^ 1][ch0 * 8]);
      gload16(bg1 + kt, &Bs[cur ^ 1][ch1 * 8]);
      asm volatile("s_waitcnt vmcnt(6)" ::: "memory");  // B(t) landed
    } else {
      asm volatile("s_waitcnt vmcnt(0)" ::: "memory");
    }
    __builtin_amdgcn_s_barrier();
    asm volatile("" ::: "memory");

    bf16x8 af[4], bfr[4];
#pragma unroll
    for (int m = 0; m < 4; ++m) {
      const int row = wr * 64 + m * 16 + cc;
      af[m] = *(const bf16x8*)&As[cur][row * 32 + (cr ^ ((row >> 1) & 3)) * 8];
    }
#pragma unroll
    for (int n = 0; n < 4; ++n) {
      const int row = wc * 64 + n * 16 + cc;
      bfr[n] = *(const bf16x8*)&Bs[cur][row * 32 + (cr ^ ((row >> 1) & 3)) * 8];
    }
#pragma unroll
    for (int m = 0; m < 4; ++m)
#pragma unroll
      for (int n = 0; n < 4; ++n)
        acc[m][n] =
            __builtin_amdgcn_mfma_f32_16x16x32_bf16(af[m], bfr[n], acc[m][n], 0, 0, 0);

    if (more) {  // write-late: cvt + ds_write A(t+1) into the other buffer
      *(bf16x8*)&As[cur ^ 1][ch0 * 8] = cvt8r(ra0, ra1);
      *(bf16x8*)&As[cur ^ 1][ch1 * 8] = cvt8r(rb0, rb1);
    }
    asm volatile("s_waitcnt lgkmcnt(0)" ::: "memory");
    __builtin_amdgcn_s_barrier();
  }

#pragma unroll
  for (int n = 0; n < 4; ++n) {
    const size_t col = n0 + wc * 64 + n * 16 + cc;
    const float bval = bias[col];
#pragma unroll
    for (int m = 0; m < 4; ++m) {
      const size_t row0 = m0 + wr * 64 + m * 16 + cr * 4;
#pragma unroll
      for (int r = 0; r < 4; ++r)
        C[(row0 + r) * N + col] = f2bf(acc[m][n][r] + bval);
    }
  }
}

// ---- GEMM (bf16 x bf16): C = A @ W^T + bias, out f32 -----------------------
// 2-phase double buffer, 4 gload_lds/stage -> vmcnt(4).

__global__ __launch_bounds__(256) void gemm_bf16a_2ph(
    const ushort* __restrict__ A, const ushort* __restrict__ B,
    const float* __restrict__ bias, float* __restrict__ C, int N, int K) {
  __shared__ __align__(16) ushort As[2][128 * 32];
  __shared__ __align__(16) ushort Bs[2][128 * 32];
  const int tid = threadIdx.x, lane = tid & 63;
  const int wv = tid >> 6, wr = wv >> 1, wc = wv & 1;
  const int cc = lane & 15, cr = lane >> 4;
  const int ntiles = N >> 7;
  const int work = xcd_swizzle(blockIdx.x, gridDim.x);
  const size_t m0 = (size_t)(work / ntiles) * 128;
  const size_t n0 = (size_t)(work % ntiles) * 128;

  const int ch0 = tid, ch1 = tid + 256;
  const int row0 = ch0 >> 2, u0 = ch0 & 3;
  const int row1 = ch1 >> 2, u1 = ch1 & 3;
  const int sw0 = (u0 ^ ((row0 >> 1) & 3)) * 8;
  const int sw1 = (u1 ^ ((row1 >> 1) & 3)) * 8;
  const ushort* a0 = A + (m0 + row0) * (size_t)K + sw0;
  const ushort* a1 = A + (m0 + row1) * (size_t)K + sw1;
  const ushort* b0 = B + (n0 + row0) * (size_t)K + sw0;
  const ushort* b1 = B + (n0 + row1) * (size_t)K + sw1;

  auto stage = [&](int bf, int kt) {
    gload16(a0 + kt, &As[bf][ch0 * 8]);
    gload16(a1 + kt, &As[bf][ch1 * 8]);
    gload16(b0 + kt, &Bs[bf][ch0 * 8]);
    gload16(b1 + kt, &Bs[bf][ch1 * 8]);
  };

  f32x4 acc[4][4] = {};
  const int nt = K >> 5;

  stage(0, 0);
  for (int t = 0; t < nt; ++t) {
    const int cur = t & 1;
    if (t + 1 < nt) {
      stage(cur ^ 1, (t + 1) << 5);
      asm volatile("s_waitcnt vmcnt(4)" ::: "memory");
    } else {
      asm volatile("s_waitcnt vmcnt(0)" ::: "memory");
    }
    __builtin_amdgcn_s_barrier();
    asm volatile("" ::: "memory");

    bf16x8 af[4], bfr[4];
#pragma unroll
    for (int m = 0; m < 4; ++m) {
      const int row = wr * 64 + m * 16 + cc;
      af[m] = *(const bf16x8*)&As[cur][row * 32 + (cr ^ ((row >> 1) & 3)) * 8];
    }
#pragma unroll
    for (int n = 0; n < 4; ++n) {
      const int row = wc * 64 + n * 16 + cc;
      bfr[n] = *(const bf16x8*)&Bs[cur][row * 32 + (cr ^ ((row >> 1) & 3)) * 8];
    }
#pragma unroll
    for (int m = 0; m < 4; ++m)
#pragma unroll
      for (int n = 0; n < 4; ++n)
        acc[m][n] =
            __builtin_amdgcn_mfma_f32_16x16x32_bf16(af[m], bfr[n], acc[m][n], 0, 0, 0);

    asm volatile("" ::: "memory");
    __builtin_amdgcn_s_barrier();
  }

#pragma unroll
  for (int n = 0; n < 4; ++n) {
    const size_t col = n0 + wc * 64 + n * 16 + cc;
    const float bval = bias[col];
#pragma unroll
    for (int m = 0; m < 4; ++m) {
      const size_t r0 = m0 + wr * 64 + m * 16 + cr * 4;
#pragma unroll
      for (int r = 0; r < 4; ++r)
        C[(r0 + r) * N + col] = acc[m][n][r] + bval;
    }
  }
}

// ---- windowed attention ----------------------------------------------------
// grid = B*H*NW = 1024 blocks, 256 threads (4 waves x 64 q-rows).
// q/k/v: bf16 [B*S, D] with col = h*64+dk. Output written in-place over q.

__global__ __launch_bounds__(256) void attn_kernel(
    const ushort* __restrict__ q, const ushort* __restrict__ k,
    const ushort* __restrict__ v, ushort* __restrict__ x) {
  __shared__ ushort Ks[256 * 72];       // K tile, padded stride 72
  __shared__ ushort Vt[64 * 264];       // V transposed [dk][s], padded stride 264
  __shared__ ushort Pw[4][16 * 264];    // per-wave P chunk [16 q-rows][256 cols]
  const int bid = blockIdx.x;
  const int w = bid & 15, h = (bid >> 4) & 15, b = bid >> 8;
  const int tid = threadIdx.x, lane = tid & 63, wv = tid >> 6;
  const int cc = lane & 15, cr = lane >> 4;
  const size_t base = ((size_t)b * 4096 + (size_t)w * 256) * 1024 + h * 64;

#pragma unroll
  for (int i = 0; i < 8; ++i) {
    const int ch = i * 256 + tid;
    const int row = ch >> 3, kc = ch & 7;
    bf16x8 val = *(const bf16x8*)(k + base + (size_t)row * 1024 + kc * 8);
    *(bf16x8*)&Ks[row * 72 + kc * 8] = val;
  }
  {
    const ushort* vp = v + base + (size_t)tid * 1024;
#pragma unroll
    for (int j = 0; j < 8; ++j) {
      bf16x8 vvv = *(const bf16x8*)(vp + j * 8);
#pragma unroll
      for (int e = 0; e < 8; ++e)
        Vt[(j * 8 + e) * 264 + tid] = __builtin_bit_cast(ushort, (__bf16)vvv[e]);
    }
  }
  __syncthreads();

  ushort* Pp = Pw[wv];
  for (int c = 0; c < 4; ++c) {
    const int qrow0 = wv * 64 + c * 16;
    const ushort* qp = q + base + (size_t)(qrow0 + cc) * 1024 + cr * 8;
    const bf16x8 qf0 = *(const bf16x8*)qp;
    const bf16x8 qf1 = *(const bf16x8*)(qp + 32);

    f32x4 sc[16];
#pragma unroll
    for (int cb = 0; cb < 16; ++cb) {
      const bf16x8 kb0 = *(const bf16x8*)&Ks[(cb * 16 + cc) * 72 + cr * 8];
      const bf16x8 kb1 = *(const bf16x8*)&Ks[(cb * 16 + cc) * 72 + 32 + cr * 8];
      f32x4 z = {0.f, 0.f, 0.f, 0.f};
      z = __builtin_amdgcn_mfma_f32_16x16x32_bf16(qf0, kb0, z, 0, 0, 0);
      z = __builtin_amdgcn_mfma_f32_16x16x32_bf16(qf1, kb1, z, 0, 0, 0);
      sc[cb] = z;
    }

    float inv[4];
#pragma unroll
    for (int r = 0; r < 4; ++r) {
      float mx = -1e30f;
#pragma unroll
      for (int cb = 0; cb < 16; ++cb) mx = fmaxf(mx, sc[cb][r]);
      mx = fmaxf(mx, __shfl_xor(mx, 1));
      mx = fmaxf(mx, __shfl_xor(mx, 2));
      mx = fmaxf(mx, __shfl_xor(mx, 4));
      mx = fmaxf(mx, __shfl_xor(mx, 8));
      float sum = 0.f;
#pragma unroll
      for (int cb = 0; cb < 16; ++cb) {
        const float p = __expf((sc[cb][r] - mx) * 0.125f);
        sc[cb][r] = p;
        sum += p;
      }
      sum += __shfl_xor(sum, 1);
      sum += __shfl_xor(sum, 2);
      sum += __shfl_xor(sum, 4);
      sum += __shfl_xor(sum, 8);
      inv[r] = 1.f / sum;
    }

#pragma unroll
    for (int r = 0; r < 4; ++r)
#pragma unroll
      for (int cb = 0; cb < 16; ++cb)
        Pp[(cr * 4 + r) * 264 + cb * 16 + cc] = f2bf(sc[cb][r]);

    bf16x8 pf[8];
#pragma unroll
    for (int ks = 0; ks < 8; ++ks)
      pf[ks] = *(const bf16x8*)&Pp[cc * 264 + ks * 32 + cr * 8];
    f32x4 o[4] = {};
#pragma unroll
    for (int db = 0; db < 4; ++db)
#pragma unroll
      for (int ks = 0; ks < 8; ++ks) {
        const bf16x8 bv = *(const bf16x8*)&Vt[(db * 16 + cc) * 264 + ks * 32 + cr * 8];
        o[db] = __builtin_amdgcn_mfma_f32_16x16x32_bf16(pf[ks], bv, o[db], 0, 0, 0);
      }

#pragma unroll
    for (int db = 0; db < 4; ++db)
#pragma unroll
      for (int r = 0; r < 4; ++r) {
        const int qr = qrow0 + cr * 4 + r;
        x[base + (size_t)qr * 1024 + db * 16 + cc] = f2bf(o[db][r] * inv[r]);
      }
  }
}

// ---- launch ----------------------------------------------------------------

extern "C" void kernel_launch(void* const* d_in, const int* in_sizes, int n_in,
                              void* d_out, int out_size, void* d_ws, size_t ws_size,
                              hipStream_t stream) {
  const float* query = (const float*)d_in[0];
  const float* key_  = (const float*)d_in[1];
  const float* value = (const float*)d_in[2];
  const float* Wq = (const float*)d_in[3];
  const float* bq = (const float*)d_in[4];
  const float* Wk = (const float*)d_in[5];
  const float* bk = (const float*)d_in[6];
  const float* Wv = (const float*)d_in[7];
  const float* bv = (const float*)d_in[8];
  const float* Wo = (const float*)d_in[9];
  const float* bo = (const float*)d_in[10];
  float* out = (float*)d_out;

  // ws: qp/kp/vp bf16 projections (33.5 MB each) + 4 bf16 weights (2 MB each)
  const size_t MN = (size_t)16384 * 1024;
  const size_t WN = (size_t)1024 * 1024;
  ushort* qp = (ushort*)d_ws;
  ushort* kp = qp + MN;
  ushort* vp = kp + MN;
  ushort* wqb = vp + MN;
  ushort* wkb = wqb + WN;
  ushort* wvb = wkb + WN;
  ushort* wob = wvb + WN;

  const dim3 blk(256);
  const dim3 ggrid(128 * 8);  // 1024 workgroups
  const int wn8 = (int)(WN / 8);

  cvtw_kernel<<<dim3(wn8 / 256), blk, 0, stream>>>(Wq, wqb, wn8);
  cvtw_kernel<<<dim3(wn8 / 256), blk, 0, stream>>>(Wk, wkb, wn8);
  cvtw_kernel<<<dim3(wn8 / 256), blk, 0, stream>>>(Wv, wvb, wn8);
  cvtw_kernel<<<dim3(wn8 / 256), blk, 0, stream>>>(Wo, wob, wn8);

  gemm_f32a_2ph<<<ggrid, blk, 0, stream>>>(query, wqb, bq, qp, 1024, 1024);
  gemm_f32a_2ph<<<ggrid, blk, 0, stream>>>(key_,  wkb, bk, kp, 1024, 1024);
  gemm_f32a_2ph<<<ggrid, blk, 0, stream>>>(value, wvb, bv, vp, 1024, 1024);

  attn_kernel<<<dim3(1024), blk, 0, stream>>>(qp, kp, vp, qp /*in-place*/);

  gemm_bf16a_2ph<<<ggrid, blk, 0, stream>>>(qp, wob, bo, out, 1024, 1024);
}

// Round 8
// 378.595 us; speedup vs baseline: 1.0325x; 1.0325x over previous
//
#include <hip/hip_runtime.h>
#include <hip/hip_bf16.h>

typedef __attribute__((ext_vector_type(8))) __bf16 bf16x8;
typedef __attribute__((ext_vector_type(4))) float f32x4;

#define DEVI static __device__ __forceinline__

// ---- helpers ---------------------------------------------------------------

DEVI ushort f2bf(float f) {
  unsigned u = __builtin_bit_cast(unsigned, f);
  return (ushort)((u + 0x7fffu + ((u >> 16) & 1u)) >> 16);
}

union BF8 { unsigned u[4]; bf16x8 v; };

DEVI bf16x8 cvt8(const float* __restrict__ p) {
  const f32x4 a = *(const f32x4*)p;
  const f32x4 b = *(const f32x4*)(p + 4);
  BF8 r;
  asm("v_cvt_pk_bf16_f32 %0, %1, %2" : "=v"(r.u[0]) : "v"(a.x), "v"(a.y));
  asm("v_cvt_pk_bf16_f32 %0, %1, %2" : "=v"(r.u[1]) : "v"(a.z), "v"(a.w));
  asm("v_cvt_pk_bf16_f32 %0, %1, %2" : "=v"(r.u[2]) : "v"(b.x), "v"(b.y));
  asm("v_cvt_pk_bf16_f32 %0, %1, %2" : "=v"(r.u[3]) : "v"(b.z), "v"(b.w));
  return r.v;
}

DEVI bf16x8 cvt8r(f32x4 a, f32x4 b) {
  BF8 r;
  asm("v_cvt_pk_bf16_f32 %0, %1, %2" : "=v"(r.u[0]) : "v"(a.x), "v"(a.y));
  asm("v_cvt_pk_bf16_f32 %0, %1, %2" : "=v"(r.u[1]) : "v"(a.z), "v"(a.w));
  asm("v_cvt_pk_bf16_f32 %0, %1, %2" : "=v"(r.u[2]) : "v"(b.x), "v"(b.y));
  asm("v_cvt_pk_bf16_f32 %0, %1, %2" : "=v"(r.u[3]) : "v"(b.z), "v"(b.w));
  return r.v;
}

DEVI void gload16(const void* g, void* l) {
  __builtin_amdgcn_global_load_lds(
      (const __attribute__((address_space(1))) unsigned*)g,
      (__attribute__((address_space(3))) unsigned*)l, 16, 0, 0);
}

DEVI int xcd_swizzle(int bid, int nwg) {
  return (bid & 7) * (nwg >> 3) + (bid >> 3);
}

// ---- weight convert f32 -> bf16 (4 MB each, ~1 us) -------------------------

__global__ __launch_bounds__(256) void cvtw_kernel(
    const float* __restrict__ in, ushort* __restrict__ out, int n8) {
  const int i = blockIdx.x * blockDim.x + threadIdx.x;
  if (i < n8) *(bf16x8*)(out + (size_t)i * 8) = cvt8(in + (size_t)i * 8);
}

// ---- GEMM (f32 A reg-staged, bf16 W): C = A @ W^T + bias, out bf16 ---------
// 128x128 tile, BK=32, 256 threads. Depth-2 pipeline: B 3-deep via
// global_load_lds (tile t+2 issued at iter t), A reg-staged 2-deep with
// named reg sets (even/odd pair-unrolled loop) + ds_write bf16.

__global__ __launch_bounds__(256) void gemm_f32a_3d(
    const float* __restrict__ A, const ushort* __restrict__ B,
    const float* __restrict__ bias, ushort* __restrict__ C, int N, int K) {
  __shared__ __align__(16) ushort As[2][4096];
  __shared__ __align__(16) ushort Bs[3][4096];
  const int tid = threadIdx.x, lane = tid & 63;
  const int wv = tid >> 6, wr = wv >> 1, wc = wv & 1;
  const int cc = lane & 15, cr = lane >> 4;
  const int ntiles = N >> 7;
  const int work = xcd_swizzle(blockIdx.x, gridDim.x);
  const size_t m0 = (size_t)(work / ntiles) * 128;
  const size_t n0 = (size_t)(work % ntiles) * 128;

  // 512 chunks of 8 elems per tile, 2 per thread; pre-swizzled source
  const int ch0 = tid, ch1 = tid + 256;
  const int ar0 = ch0 >> 2, au0 = ch0 & 3;
  const int ar1 = ch1 >> 2, au1 = ch1 & 3;
  const int ko0 = (au0 ^ ((ar0 >> 1) & 3)) * 8;
  const int ko1 = (au1 ^ ((ar1 >> 1) & 3)) * 8;
  const float* ag0 = A + (m0 + ar0) * (size_t)K + ko0;
  const float* ag1 = A + (m0 + ar1) * (size_t)K + ko1;
  const ushort* bg0 = B + (n0 + ar0) * (size_t)K + ko0;
  const ushort* bg1 = B + (n0 + ar1) * (size_t)K + ko1;

  f32x4 acc[4][4] = {};
  const int nt = K >> 5;  // 32, even

  auto compute = [&](const ushort* __restrict__ Ab,
                     const ushort* __restrict__ Bb) {
    bf16x8 af[4], bfr[4];
#pragma unroll
    for (int m = 0; m < 4; ++m) {
      const int row = wr * 64 + m * 16 + cc;
      af[m] = *(const bf16x8*)&Ab[row * 32 + (cr ^ ((row >> 1) & 3)) * 8];
    }
#pragma unroll
    for (int n = 0; n < 4; ++n) {
      const int row = wc * 64 + n * 16 + cc;
      bfr[n] = *(const bf16x8*)&Bb[row * 32 + (cr ^ ((row >> 1) & 3)) * 8];
    }
#pragma unroll
    for (int m = 0; m < 4; ++m)
#pragma unroll
      for (int n = 0; n < 4; ++n)
        acc[m][n] =
            __builtin_amdgcn_mfma_f32_16x16x32_bf16(af[m], bfr[n], acc[m][n], 0, 0, 0);
  };

  f32x4 pa0, pa1, pa2, pa3;  // reg set A (even tiles' next A)
  f32x4 pb0, pb1, pb2, pb3;  // reg set B (odd tiles' next A)

  // prologue: B(0),B(1) -> LDS; A(0),A(1) -> regs; A(0) -> As[0]
  gload16(bg0, &Bs[0][ch0 * 8]);
  gload16(bg1, &Bs[0][ch1 * 8]);
  gload16(bg0 + 32, &Bs[1][ch0 * 8]);
  gload16(bg1 + 32, &Bs[1][ch1 * 8]);
  pa0 = *(const f32x4*)(ag0);      pa1 = *(const f32x4*)(ag0 + 4);
  pa2 = *(const f32x4*)(ag1);      pa3 = *(const f32x4*)(ag1 + 4);
  pb0 = *(const f32x4*)(ag0 + 32); pb1 = *(const f32x4*)(ag0 + 36);
  pb2 = *(const f32x4*)(ag1 + 32); pb3 = *(const f32x4*)(ag1 + 36);
  *(bf16x8*)&As[0][ch0 * 8] = cvt8r(pa0, pa1);
  *(bf16x8*)&As[0][ch1 * 8] = cvt8r(pa2, pa3);
  asm volatile("s_waitcnt lgkmcnt(0)" ::: "memory");

  for (int t = 0; t < nt; t += 2) {
    // ---- even sub-iter: tile t from As[0], Bs[t%3] ----
    if (t + 2 < nt) {
      gload16(bg0 + (t + 2) * 32, &Bs[(t + 2) % 3][ch0 * 8]);
      gload16(bg1 + (t + 2) * 32, &Bs[(t + 2) % 3][ch1 * 8]);
    }
    asm volatile("s_waitcnt vmcnt(8)" ::: "memory");
    __builtin_amdgcn_s_barrier();
    asm volatile("" ::: "memory");
    compute(As[0], Bs[t % 3]);
    if (t + 2 < nt) {
      const int kt = (t + 2) * 32;
      pa0 = *(const f32x4*)(ag0 + kt); pa1 = *(const f32x4*)(ag0 + kt + 4);
      pa2 = *(const f32x4*)(ag1 + kt); pa3 = *(const f32x4*)(ag1 + kt + 4);
    }
    *(bf16x8*)&As[1][ch0 * 8] = cvt8r(pb0, pb1);  // A(t+1) publish
    *(bf16x8*)&As[1][ch1 * 8] = cvt8r(pb2, pb3);
    asm volatile("s_waitcnt lgkmcnt(0)" ::: "memory");
    __builtin_amdgcn_s_barrier();

    // ---- odd sub-iter: tile t+1 from As[1], Bs[(t+1)%3] ----
    if (t + 3 < nt) {
      gload16(bg0 + (t + 3) * 32, &Bs[(t + 3) % 3][ch0 * 8]);
      gload16(bg1 + (t + 3) * 32, &Bs[(t + 3) % 3][ch1 * 8]);
    }
    asm volatile("s_waitcnt vmcnt(8)" ::: "memory");
    __builtin_amdgcn_s_barrier();
    asm volatile("" ::: "memory");
    compute(As[1], Bs[(t + 1) % 3]);
    if (t + 3 < nt) {
      const int kt = (t + 3) * 32;
      pb0 = *(const f32x4*)(ag0 + kt); pb1 = *(const f32x4*)(ag0 + kt + 4);
      pb2 = *(const f32x4*)(ag1 + kt); pb3 = *(const f32x4*)(ag1 + kt + 4);
    }
    if (t + 2 < nt) {
      *(bf16x8*)&As[0][ch0 * 8] = cvt8r(pa0, pa1);  // A(t+2) publish
      *(bf16x8*)&As[0][ch1 * 8] = cvt8r(pa2, pa3);
      asm volatile("s_waitcnt lgkmcnt(0)" ::: "memory");
    }
    __builtin_amdgcn_s_barrier();
  }

#pragma unroll
  for (int n = 0; n < 4; ++n) {
    const size_t col = n0 + wc * 64 + n * 16 + cc;
    const float bval = bias[col];
#pragma unroll
    for (int m = 0; m < 4; ++m) {
      const size_t row0 = m0 + wr * 64 + m * 16 + cr * 4;
#pragma unroll
      for (int r = 0; r < 4; ++r)
        C[(row0 + r) * N + col] = f2bf(acc[m][n][r] + bval);
    }
  }
}

// ---- GEMM (bf16 x bf16): C = A @ W^T + bias, out f32 -----------------------
// Depth-2 pipeline, 3-deep LDS buffers on both operands, counted vmcnt.

__global__ __launch_bounds__(256) void gemm_bf16a_3d(
    const ushort* __restrict__ A, const ushort* __restrict__ B,
    const float* __restrict__ bias, float* __restrict__ C, int N, int K) {
  __shared__ __align__(16) ushort As[3][4096];
  __shared__ __align__(16) ushort Bs[3][4096];
  const int tid = threadIdx.x, lane = tid & 63;
  const int wv = tid >> 6, wr = wv >> 1, wc = wv & 1;
  const int cc = lane & 15, cr = lane >> 4;
  const int ntiles = N >> 7;
  const int work = xcd_swizzle(blockIdx.x, gridDim.x);
  const size_t m0 = (size_t)(work / ntiles) * 128;
  const size_t n0 = (size_t)(work % ntiles) * 128;

  const int ch0 = tid, ch1 = tid + 256;
  const int row0 = ch0 >> 2, u0 = ch0 & 3;
  const int row1 = ch1 >> 2, u1 = ch1 & 3;
  const int sw0 = (u0 ^ ((row0 >> 1) & 3)) * 8;
  const int sw1 = (u1 ^ ((row1 >> 1) & 3)) * 8;
  const ushort* a0 = A + (m0 + row0) * (size_t)K + sw0;
  const ushort* a1 = A + (m0 + row1) * (size_t)K + sw1;
  const ushort* b0 = B + (n0 + row0) * (size_t)K + sw0;
  const ushort* b1 = B + (n0 + row1) * (size_t)K + sw1;

  auto stage = [&](int bf, int kt) {
    gload16(a0 + kt, &As[bf][ch0 * 8]);
    gload16(a1 + kt, &As[bf][ch1 * 8]);
    gload16(b0 + kt, &Bs[bf][ch0 * 8]);
    gload16(b1 + kt, &Bs[bf][ch1 * 8]);
  };

  f32x4 acc[4][4] = {};
  const int nt = K >> 5;

  stage(0, 0);
  stage(1, 32);
  for (int t = 0; t < nt; ++t) {
    if (t + 2 < nt) {
      stage((t + 2) % 3, (t + 2) * 32);
      asm volatile("s_waitcnt vmcnt(8)" ::: "memory");
    } else if (t + 1 < nt) {
      asm volatile("s_waitcnt vmcnt(4)" ::: "memory");
    } else {
      asm volatile("s_waitcnt vmcnt(0)" ::: "memory");
    }
    __builtin_amdgcn_s_barrier();
    asm volatile("" ::: "memory");

    const ushort* Ab = As[t % 3];
    const ushort* Bb = Bs[t % 3];
    bf16x8 af[4], bfr[4];
#pragma unroll
    for (int m = 0; m < 4; ++m) {
      const int row = wr * 64 + m * 16 + cc;
      af[m] = *(const bf16x8*)&Ab[row * 32 + (cr ^ ((row >> 1) & 3)) * 8];
    }
#pragma unroll
    for (int n = 0; n < 4; ++n) {
      const int row = wc * 64 + n * 16 + cc;
      bfr[n] = *(const bf16x8*)&Bb[row * 32 + (cr ^ ((row >> 1) & 3)) * 8];
    }
#pragma unroll
    for (int m = 0; m < 4; ++m)
#pragma unroll
      for (int n = 0; n < 4; ++n)
        acc[m][n] =
            __builtin_amdgcn_mfma_f32_16x16x32_bf16(af[m], bfr[n], acc[m][n], 0, 0, 0);

    asm volatile("" ::: "memory");
    __builtin_amdgcn_s_barrier();
  }

#pragma unroll
  for (int n = 0; n < 4; ++n) {
    const size_t col = n0 + wc * 64 + n * 16 + cc;
    const float bval = bias[col];
#pragma unroll
    for (int m = 0; m < 4; ++m) {
      const size_t r0 = m0 + wr * 64 + m * 16 + cr * 4;
#pragma unroll
      for (int r = 0; r < 4; ++r)
        C[(r0 + r) * N + col] = acc[m][n][r] + bval;
    }
  }
}

// ---- windowed attention ----------------------------------------------------

__global__ __launch_bounds__(256) void attn_kernel(
    const ushort* __restrict__ q, const ushort* __restrict__ k,
    const ushort* __restrict__ v, ushort* __restrict__ x) {
  __shared__ ushort Ks[256 * 72];
  __shared__ ushort Vt[64 * 264];
  __shared__ ushort Pw[4][16 * 264];
  const int bid = blockIdx.x;
  const int w = bid & 15, h = (bid >> 4) & 15, b = bid >> 8;
  const int tid = threadIdx.x, lane = tid & 63, wv = tid >> 6;
  const int cc = lane & 15, cr = lane >> 4;
  const size_t base = ((size_t)b * 4096 + (size_t)w * 256) * 1024 + h * 64;

#pragma unroll
  for (int i = 0; i < 8; ++i) {
    const int ch = i * 256 + tid;
    const int row = ch >> 3, kc = ch & 7;
    bf16x8 val = *(const bf16x8*)(k + base + (size_t)row * 1024 + kc * 8);
    *(bf16x8*)&Ks[row * 72 + kc * 8] = val;
  }
  {
    const ushort* vp = v + base + (size_t)tid * 1024;
#pragma unroll
    for (int j = 0; j < 8; ++j) {
      bf16x8 vvv = *(const bf16x8*)(vp + j * 8);
#pragma unroll
      for (int e = 0; e < 8; ++e)
        Vt[(j * 8 + e) * 264 + tid] = __builtin_bit_cast(ushort, (__bf16)vvv[e]);
    }
  }
  __syncthreads();

  ushort* Pp = Pw[wv];
  for (int c = 0; c < 4; ++c) {
    const int qrow0 = wv * 64 + c * 16;
    const ushort* qp = q + base + (size_t)(qrow0 + cc) * 1024 + cr * 8;
    const bf16x8 qf0 = *(const bf16x8*)qp;
    const bf16x8 qf1 = *(const bf16x8*)(qp + 32);

    f32x4 sc[16];
#pragma unroll
    for (int cb = 0; cb < 16; ++cb) {
      const bf16x8 kb0 = *(const bf16x8*)&Ks[(cb * 16 + cc) * 72 + cr * 8];
      const bf16x8 kb1 = *(const bf16x8*)&Ks[(cb * 16 + cc) * 72 + 32 + cr * 8];
      f32x4 z = {0.f, 0.f, 0.f, 0.f};
      z = __builtin_amdgcn_mfma_f32_16x16x32_bf16(qf0, kb0, z, 0, 0, 0);
      z = __builtin_amdgcn_mfma_f32_16x16x32_bf16(qf1, kb1, z, 0, 0, 0);
      sc[cb] = z;
    }

    float inv[4];
#pragma unroll
    for (int r = 0; r < 4; ++r) {
      float mx = -1e30f;
#pragma unroll
      for (int cb = 0; cb < 16; ++cb) mx = fmaxf(mx, sc[cb][r]);
      mx = fmaxf(mx, __shfl_xor(mx, 1));
      mx = fmaxf(mx, __shfl_xor(mx, 2));
      mx = fmaxf(mx, __shfl_xor(mx, 4));
      mx = fmaxf(mx, __shfl_xor(mx, 8));
      float sum = 0.f;
#pragma unroll
      for (int cb = 0; cb < 16; ++cb) {
        const float p = __expf((sc[cb][r] - mx) * 0.125f);
        sc[cb][r] = p;
        sum += p;
      }
      sum += __shfl_xor(sum, 1);
      sum += __shfl_xor(sum, 2);
      sum += __shfl_xor(sum, 4);
      sum += __shfl_xor(sum, 8);
      inv[r] = 1.f / sum;
    }

#pragma unroll
    for (int r = 0; r < 4; ++r)
#pragma unroll
      for (int cb = 0; cb < 16; ++cb)
        Pp[(cr * 4 + r) * 264 + cb * 16 + cc] = f2bf(sc[cb][r]);

    bf16x8 pf[8];
#pragma unroll
    for (int ks = 0; ks < 8; ++ks)
      pf[ks] = *(const bf16x8*)&Pp[cc * 264 + ks * 32 + cr * 8];
    f32x4 o[4] = {};
#pragma unroll
    for (int db = 0; db < 4; ++db)
#pragma unroll
      for (int ks = 0; ks < 8; ++ks) {
        const bf16x8 bv = *(const bf16x8*)&Vt[(db * 16 + cc) * 264 + ks * 32 + cr * 8];
        o[db] = __builtin_amdgcn_mfma_f32_16x16x32_bf16(pf[ks], bv, o[db], 0, 0, 0);
      }

#pragma unroll
    for (int db = 0; db < 4; ++db)
#pragma unroll
      for (int r = 0; r < 4; ++r) {
        const int qr = qrow0 + cr * 4 + r;
        x[base + (size_t)qr * 1024 + db * 16 + cc] = f2bf(o[db][r] * inv[r]);
      }
  }
}

// ---- launch ----------------------------------------------------------------

extern "C" void kernel_launch(void* const* d_in, const int* in_sizes, int n_in,
                              void* d_out, int out_size, void* d_ws, size_t ws_size,
                              hipStream_t stream) {
  const float* query = (const float*)d_in[0];
  const float* key_  = (const float*)d_in[1];
  const float* value = (const float*)d_in[2];
  const float* Wq = (const float*)d_in[3];
  const float* bq = (const float*)d_in[4];
  const float* Wk = (const float*)d_in[5];
  const float* bk = (const float*)d_in[6];
  const float* Wv = (const float*)d_in[7];
  const float* bv = (const float*)d_in[8];
  const float* Wo = (const float*)d_in[9];
  const float* bo = (const float*)d_in[10];
  float* out = (float*)d_out;

  const size_t MN = (size_t)16384 * 1024;
  const size_t WN = (size_t)1024 * 1024;
  ushort* qp = (ushort*)d_ws;
  ushort* kp = qp + MN;
  ushort* vp = kp + MN;
  ushort* wqb = vp + MN;
  ushort* wkb = wqb + WN;
  ushort* wvb = wkb + WN;
  ushort* wob = wvb + WN;

  const dim3 blk(256);
  const dim3 ggrid(128 * 8);  // 1024 workgroups
  const int wn8 = (int)(WN / 8);

  cvtw_kernel<<<dim3(wn8 / 256), blk, 0, stream>>>(Wq, wqb, wn8);
  cvtw_kernel<<<dim3(wn8 / 256), blk, 0, stream>>>(Wk, wkb, wn8);
  cvtw_kernel<<<dim3(wn8 / 256), blk, 0, stream>>>(Wv, wvb, wn8);
  cvtw_kernel<<<dim3(wn8 / 256), blk, 0, stream>>>(Wo, wob, wn8);

  gemm_f32a_3d<<<ggrid, blk, 0, stream>>>(query, wqb, bq, qp, 1024, 1024);
  gemm_f32a_3d<<<ggrid, blk, 0, stream>>>(key_,  wkb, bk, kp, 1024, 1024);
  gemm_f32a_3d<<<ggrid, blk, 0, stream>>>(value, wvb, bv, vp, 1024, 1024);

  attn_kernel<<<dim3(1024), blk, 0, stream>>>(qp, kp, vp, qp /*in-place*/);

  gemm_bf16a_3d<<<ggrid, blk, 0, stream>>>(qp, wob, bo, out, 1024, 1024);
}